// Round 2
// baseline (268.073 us; speedup 1.0000x reference)
//
#include <hip/hip_runtime.h>
#include <hip/hip_bf16.h>

typedef unsigned short u16;
using short8  = __attribute__((ext_vector_type(8))) short;
using floatx4 = __attribute__((ext_vector_type(4))) float;

#define KPAD 104   // padded k-extent (bf16 elems); 52 words/row, gcd(52,32)=4 -> conflict-free frags

__device__ __forceinline__ u16 f2bf(float f) {
  union { float f; unsigned u; } v; v.f = f;
  unsigned r = v.u + 0x7fffu + ((v.u >> 16) & 1u);   // RNE
  return (u16)(r >> 16);
}

// ---------------- Kernel 0: W_eff = W2 (81x162) @ W1 (162x81), fp32 in/out ----------------
__global__ __launch_bounds__(256) void k_weff(const float* __restrict__ W1,
                                              const float* __restrict__ W2,
                                              float* __restrict__ we) {
  int idx = blockIdx.x * 256 + threadIdx.x;
  if (idx >= 81 * 81) return;
  int kp = idx / 81, k = idx - kp * 81;
  float s = 0.f;
  #pragma unroll 6
  for (int m = 0; m < 162; ++m)
    s = fmaf(W2[kp * 162 + m], W1[m * 81 + k], s);
  we[idx] = s;
}

// ---------------- Kernel 1: conv1x1 + bias, fused unfold, fp32 in -> bf16 out ----------------
// V layout: [(tensor*32 + o)*1024 + l][81], l = pd*256+pw, k = kd*9+kw
__global__ __launch_bounds__(256) void k_conv(const float* __restrict__ xg,
                                              const float* __restrict__ yg,
                                              const float* __restrict__ Wi,
                                              const float* __restrict__ bi,
                                              const float* __restrict__ Wf,
                                              const float* __restrict__ bfe,
                                              u16* __restrict__ V) {
  __shared__ float Ws[1024];
  __shared__ float bs[32];
  int tensor = blockIdx.y;
  const float* src = tensor ? yg : xg;
  const float* Wg  = tensor ? Wf : Wi;
  const float* bg  = tensor ? bfe : bi;
  int t = threadIdx.x;
  for (int i = t; i < 1024; i += 256) Ws[i] = Wg[i];
  if (t < 32) bs[t] = bg[t];
  __syncthreads();

  int vbase = blockIdx.x * 512 + t;       // 162 blocks * 512 = 82944 voxels
  float xin[2][32];
  #pragma unroll
  for (int c = 0; c < 32; ++c) {
    xin[0][c] = src[c * 82944 + vbase];
    xin[1][c] = src[c * 82944 + vbase + 256];
  }
  int dst[2];
  #pragma unroll
  for (int v = 0; v < 2; ++v) {
    int vox = vbase + v * 256;
    int d  = vox / 2304, hw = vox - d * 2304;
    int pd = d / 9,  kd = d  - pd * 9;
    int pw = hw / 9, kw = hw - pw * 9;
    dst[v] = tensor * (32 * 82944) + (pd * 256 + pw) * 81 + kd * 9 + kw;
  }
  #pragma unroll
  for (int o = 0; o < 32; ++o) {
    float s0 = bs[o], s1 = bs[o];
    #pragma unroll
    for (int c = 0; c < 32; ++c) {
      float w = Ws[o * 32 + c];
      s0 = fmaf(w, xin[0][c], s0);
      s1 = fmaf(w, xin[1][c], s1);
    }
    V[dst[0] + o * 82944] = f2bf(s0);
    V[dst[1] + o * 82944] = f2bf(s1);
  }
}

// ---------------- Kernel 2: PXY = LeakyReLU(V @ W_eff^T), MFMA bf16 ----------------
// 512 blocks, 128 rows each; wave = 32 rows x 96 cols (2x6 tiles of 16x16).
__global__ __launch_bounds__(256) void k_rtrans(const u16* __restrict__ V,
                                                const float* __restrict__ we,
                                                u16* __restrict__ PXY) {
  __shared__ u16 Vt[128 * KPAD];    // 26624 B
  __shared__ u16 WeT[96 * KPAD];    // 19968 B
  int t = threadIdx.x;
  int r0 = blockIdx.x * 128;

  for (int i = t; i < 96 * KPAD; i += 256) {
    int kp = i / KPAD, k = i - kp * KPAD;
    WeT[i] = (kp < 81 && k < 81) ? f2bf(we[kp * 81 + k]) : (u16)0;
  }
  for (int i = t; i < 128 * KPAD; i += 256) {
    int r = i / KPAD, k = i - r * KPAD;
    Vt[i] = (k < 81) ? V[(r0 + r) * 81 + k] : (u16)0;
  }
  __syncthreads();

  int wave = t >> 6, lane = t & 63;
  int m15 = lane & 15, quad = lane >> 4;
  int rowbase = wave * 32;

  floatx4 acc[2][6];
  #pragma unroll
  for (int i = 0; i < 2; ++i)
    #pragma unroll
    for (int j = 0; j < 6; ++j) acc[i][j] = (floatx4){0.f, 0.f, 0.f, 0.f};

  #pragma unroll
  for (int ks = 0; ks < 96; ks += 32) {
    short8 a[2], b[6];
    #pragma unroll
    for (int i = 0; i < 2; ++i)
      a[i] = *(const short8*)&Vt[(rowbase + i * 16 + m15) * KPAD + ks + quad * 8];
    #pragma unroll
    for (int j = 0; j < 6; ++j)
      b[j] = *(const short8*)&WeT[(j * 16 + m15) * KPAD + ks + quad * 8];
    #pragma unroll
    for (int i = 0; i < 2; ++i)
      #pragma unroll
      for (int j = 0; j < 6; ++j)
        acc[i][j] = __builtin_amdgcn_mfma_f32_16x16x32_bf16(a[i], b[j], acc[i][j], 0, 0, 0);
  }

  #pragma unroll
  for (int i = 0; i < 2; ++i) {
    #pragma unroll
    for (int j = 0; j < 6; ++j) {
      int kp = j * 16 + m15;
      if (kp < 81) {
        #pragma unroll
        for (int reg = 0; reg < 4; ++reg) {
          int r = rowbase + i * 16 + quad * 4 + reg;
          float v = acc[i][j][reg];
          v = v > 0.f ? v : 0.2f * v;
          PXY[(r0 + r) * 81 + kp] = f2bf(v);
        }
      }
    }
  }
}

// ---------------- Kernel 3: att[c] = PX[c] @ PY[c]^T / 81, MFMA bf16, fp32 out ----------------
// grid (8,8,32): 128x128 out tile per block; 4 waves = 2x2 of 64x64; 4x4 MFMA tiles/wave.
__global__ __launch_bounds__(256) void k_att(const u16* __restrict__ PXY,
                                             float* __restrict__ out) {
  __shared__ u16 pxs[128 * KPAD];   // 26624 B
  __shared__ u16 pys[128 * KPAD];
  int t = threadIdx.x;
  int c = blockIdx.z;
  int l1b = blockIdx.y * 128, l2b = blockIdx.x * 128;
  const u16* px = PXY + c * 82944;          // c*1024*81
  const u16* py = PXY + (32 + c) * 82944;

  for (int i = t; i < 128 * KPAD; i += 256) {
    int r = i / KPAD, k = i - r * KPAD;
    pxs[i] = (k < 81) ? px[(l1b + r) * 81 + k] : (u16)0;
    pys[i] = (k < 81) ? py[(l2b + r) * 81 + k] : (u16)0;
  }
  __syncthreads();

  int wave = t >> 6, lane = t & 63;
  int m15 = lane & 15, quad = lane >> 4;
  int wy = (wave >> 1) * 64, wx = (wave & 1) * 64;

  floatx4 acc[4][4];
  #pragma unroll
  for (int i = 0; i < 4; ++i)
    #pragma unroll
    for (int j = 0; j < 4; ++j) acc[i][j] = (floatx4){0.f, 0.f, 0.f, 0.f};

  #pragma unroll
  for (int ks = 0; ks < 96; ks += 32) {
    short8 a[4], b[4];
    #pragma unroll
    for (int i = 0; i < 4; ++i)
      a[i] = *(const short8*)&pxs[(wy + i * 16 + m15) * KPAD + ks + quad * 8];
    #pragma unroll
    for (int j = 0; j < 4; ++j)
      b[j] = *(const short8*)&pys[(wx + j * 16 + m15) * KPAD + ks + quad * 8];
    #pragma unroll
    for (int i = 0; i < 4; ++i)
      #pragma unroll
      for (int j = 0; j < 4; ++j)
        acc[i][j] = __builtin_amdgcn_mfma_f32_16x16x32_bf16(a[i], b[j], acc[i][j], 0, 0, 0);
  }

  const float inv = 1.f / 81.f;
  #pragma unroll
  for (int i = 0; i < 4; ++i)
    #pragma unroll
    for (int j = 0; j < 4; ++j)
      #pragma unroll
      for (int reg = 0; reg < 4; ++reg) {
        int row = l1b + wy + i * 16 + quad * 4 + reg;
        int col = l2b + wx + j * 16 + m15;
        out[(c << 20) + (row << 10) + col] = acc[i][j][reg] * inv;
      }
}

extern "C" void kernel_launch(void* const* d_in, const int* in_sizes, int n_in,
                              void* d_out, int out_size, void* d_ws, size_t ws_size,
                              hipStream_t stream) {
  const float* x    = (const float*)d_in[0];
  const float* y    = (const float*)d_in[1];
  const float* Wimg = (const float*)d_in[2];
  const float* bimg = (const float*)d_in[3];
  const float* Wfea = (const float*)d_in[4];
  const float* bfea = (const float*)d_in[5];
  const float* W1   = (const float*)d_in[6];
  const float* W2   = (const float*)d_in[7];
  float* out = (float*)d_out;

  char* ws = (char*)d_ws;
  float* we  = (float*)ws;                                 //    26,244 B
  u16*   V   = (u16*)(ws + 32768);                         // 10,616,832 B
  u16*   PXY = (u16*)(ws + 32768 + 10616832);              // 10,616,832 B  (total ~20.3 MB)

  k_weff<<<26, 256, 0, stream>>>(W1, W2, we);
  k_conv<<<dim3(162, 2), 256, 0, stream>>>(x, y, Wimg, bimg, Wfea, bfea, V);
  k_rtrans<<<512, 256, 0, stream>>>(V, we, PXY);
  k_att<<<dim3(8, 8, 32), 256, 0, stream>>>(PXY, out);
}

// Round 3
// 206.025 us; speedup vs baseline: 1.3012x; 1.3012x over previous
//
#include <hip/hip_runtime.h>
#include <hip/hip_bf16.h>

typedef unsigned short u16;
using short8  = __attribute__((ext_vector_type(8))) short;
using floatx4 = __attribute__((ext_vector_type(4))) float;

#define KPAD 104   // LDS row stride (bf16 elems): 52 dwords, stride%32=20 -> 2-way (free) frag reads
#define VSTR 96    // global V row stride (bf16 elems): 192 B, 16B-aligned rows, 12 short8 per row

__device__ __forceinline__ u16 f2bf(float f) {
  union { float f; unsigned u; } v; v.f = f;
  unsigned r = v.u + 0x7fffu + ((v.u >> 16) & 1u);   // RNE
  return (u16)(r >> 16);
}

// ---------------- Kernel 1: conv1x1+bias+unfold (y=0,1) and W_eff (y=2) ----------------
// V layout: row = (tensor*32 + o)*1024 + l, stride VSTR; l = pd*256+pw, k = kd*9+kw.
// wepad: bf16 [96][104], W_eff[kp][k] = sum_m W2[kp][m]*W1[m][k], zero outside 81x81.
__global__ __launch_bounds__(256) void k_conv(const float* __restrict__ xg,
                                              const float* __restrict__ yg,
                                              const float* __restrict__ Wi,
                                              const float* __restrict__ bi,
                                              const float* __restrict__ Wf,
                                              const float* __restrict__ bfe,
                                              const float* __restrict__ W1,
                                              const float* __restrict__ W2,
                                              u16* __restrict__ V,
                                              u16* __restrict__ wepad) {
  int t = threadIdx.x;
  if (blockIdx.y == 2) {                 // ---- W_eff blocks ----
    if (blockIdx.x >= 39) return;        // 39*256 = 9984 = 96*104
    int idx = blockIdx.x * 256 + t;
    int kp = idx / 104, k = idx - kp * 104;
    float s = 0.f;
    if (kp < 81 && k < 81) {
      #pragma unroll 6
      for (int m = 0; m < 162; ++m)
        s = fmaf(W2[kp * 162 + m], W1[m * 81 + k], s);
    }
    wepad[idx] = (kp < 81 && k < 81) ? f2bf(s) : (u16)0;
    return;
  }
  // ---- conv blocks ----
  __shared__ float Ws[1024];
  __shared__ float bs[32];
  int tensor = blockIdx.y;
  const float* src = tensor ? yg : xg;
  const float* Wg  = tensor ? Wf : Wi;
  const float* bg  = tensor ? bfe : bi;
  for (int i = t; i < 1024; i += 256) Ws[i] = Wg[i];
  if (t < 32) bs[t] = bg[t];
  __syncthreads();

  int vbase = blockIdx.x * 512 + t;       // 162 blocks * 512 = 82944 voxels
  float xin[2][32];
  #pragma unroll
  for (int c = 0; c < 32; ++c) {
    xin[0][c] = src[c * 82944 + vbase];
    xin[1][c] = src[c * 82944 + vbase + 256];
  }
  int dst[2];
  #pragma unroll
  for (int v = 0; v < 2; ++v) {
    int vox = vbase + v * 256;
    int d  = vox / 2304, hw = vox - d * 2304;
    int pd = d / 9,  kd = d  - pd * 9;
    int pw = hw / 9, kw = hw - pw * 9;
    dst[v] = tensor * (32 * 1024 * VSTR) + (pd * 256 + pw) * VSTR + kd * 9 + kw;
  }
  #pragma unroll
  for (int o = 0; o < 32; ++o) {
    float s0 = bs[o], s1 = bs[o];
    #pragma unroll
    for (int c = 0; c < 32; ++c) {
      float w = Ws[o * 32 + c];
      s0 = fmaf(w, xin[0][c], s0);
      s1 = fmaf(w, xin[1][c], s1);
    }
    V[dst[0] + o * (1024 * VSTR)] = f2bf(s0);
    V[dst[1] + o * (1024 * VSTR)] = f2bf(s1);
  }
}

// ---------------- Kernel 2: fused res_trans + att ----------------
// grid (8,8,32): out tile 128(l1) x 128(l2) for channel c.
// Phase A: stage WeT + V tiles (vectorized). Phase B: per-wave P = LeakyReLU(V@WeT^T)
// for its own 32 rows, written in-place over V rows in LDS. Phase C: att = PX@PY^T/81.
__global__ __launch_bounds__(256, 2) void k_att(const u16* __restrict__ V,
                                                const u16* __restrict__ wepad,
                                                float* __restrict__ out) {
  __shared__ u16 WeT[96 * KPAD];    // 19968 B
  __shared__ u16 pxs[128 * KPAD];   // 26624 B
  __shared__ u16 pys[128 * KPAD];   // 26624 B  (total 73216 B -> 2 blocks/CU)
  int t = threadIdx.x;
  int c = blockIdx.z;
  int l1b = blockIdx.y * 128, l2b = blockIdx.x * 128;
  const u16* vx = V + ((c)      * 1024 + l1b) * VSTR;
  const u16* vy = V + ((32 + c) * 1024 + l2b) * VSTR;

  // --- Phase A: vectorized staging ---
  for (int i = t; i < 1248; i += 256)      // 96*104 elems = 1248 short8, direct copy
    *(short8*)&WeT[i * 8] = ((const short8*)wepad)[i];
  for (int i = t; i < 1536; i += 256) {    // 128 rows x 12 short8
    int r = i / 12, xx = i - r * 12;
    short8 a = *(const short8*)&vx[i * 8];  // i*8 == r*96 + xx*8
    short8 b = *(const short8*)&vy[i * 8];
    *(short8*)&pxs[r * KPAD + xx * 8] = a;
    *(short8*)&pys[r * KPAD + xx * 8] = b;
  }
  __syncthreads();

  int wave = t >> 6, lane = t & 63;
  int m15 = lane & 15, quad = lane >> 4;

  // --- Phase B: res_trans for this wave's 32 rows, in place ---
  short8 bw[6][3];
  #pragma unroll
  for (int j = 0; j < 6; ++j)
    #pragma unroll
    for (int ks = 0; ks < 3; ++ks)
      bw[j][ks] = *(const short8*)&WeT[(j * 16 + m15) * KPAD + ks * 32 + quad * 8];

  int wbase = wave * 32;
  #pragma unroll
  for (int tz = 0; tz < 2; ++tz) {
    u16* buf = tz ? pys : pxs;
    short8 a[2][3];
    #pragma unroll
    for (int i2 = 0; i2 < 2; ++i2)
      #pragma unroll
      for (int ks = 0; ks < 3; ++ks)
        a[i2][ks] = *(const short8*)&buf[(wbase + i2 * 16 + m15) * KPAD + ks * 32 + quad * 8];
    floatx4 pacc[2][6];
    #pragma unroll
    for (int i2 = 0; i2 < 2; ++i2)
      #pragma unroll
      for (int j = 0; j < 6; ++j) pacc[i2][j] = (floatx4){0.f, 0.f, 0.f, 0.f};
    #pragma unroll
    for (int ks = 0; ks < 3; ++ks)
      #pragma unroll
      for (int i2 = 0; i2 < 2; ++i2)
        #pragma unroll
        for (int j = 0; j < 6; ++j)
          pacc[i2][j] = __builtin_amdgcn_mfma_f32_16x16x32_bf16(a[i2][ks], bw[j][ks], pacc[i2][j], 0, 0, 0);
    // LeakyReLU + write P over own V rows (cols 81..95 are exactly 0: WeT rows are 0)
    #pragma unroll
    for (int i2 = 0; i2 < 2; ++i2)
      #pragma unroll
      for (int j = 0; j < 6; ++j)
        #pragma unroll
        for (int reg = 0; reg < 4; ++reg) {
          int row = wbase + i2 * 16 + quad * 4 + reg;
          int col = j * 16 + m15;
          float v = pacc[i2][j][reg];
          v = v > 0.f ? v : 0.2f * v;
          buf[row * KPAD + col] = f2bf(v);
        }
  }
  __syncthreads();

  // --- Phase C: att tile ---
  int wy = (wave >> 1) * 64, wx = (wave & 1) * 64;
  floatx4 acc[4][4];
  #pragma unroll
  for (int i = 0; i < 4; ++i)
    #pragma unroll
    for (int j = 0; j < 4; ++j) acc[i][j] = (floatx4){0.f, 0.f, 0.f, 0.f};

  #pragma unroll
  for (int ks = 0; ks < 3; ++ks) {
    short8 a[4], b[4];
    #pragma unroll
    for (int i = 0; i < 4; ++i)
      a[i] = *(const short8*)&pxs[(wy + i * 16 + m15) * KPAD + ks * 32 + quad * 8];
    #pragma unroll
    for (int j = 0; j < 4; ++j)
      b[j] = *(const short8*)&pys[(wx + j * 16 + m15) * KPAD + ks * 32 + quad * 8];
    #pragma unroll
    for (int i = 0; i < 4; ++i)
      #pragma unroll
      for (int j = 0; j < 4; ++j)
        acc[i][j] = __builtin_amdgcn_mfma_f32_16x16x32_bf16(a[i], b[j], acc[i][j], 0, 0, 0);
  }

  const float inv = 1.f / 81.f;
  #pragma unroll
  for (int i = 0; i < 4; ++i)
    #pragma unroll
    for (int j = 0; j < 4; ++j)
      #pragma unroll
      for (int reg = 0; reg < 4; ++reg) {
        int row = l1b + wy + i * 16 + quad * 4 + reg;
        int col = l2b + wx + j * 16 + m15;
        out[(c << 20) + (row << 10) + col] = acc[i][j][reg] * inv;
      }
}

extern "C" void kernel_launch(void* const* d_in, const int* in_sizes, int n_in,
                              void* d_out, int out_size, void* d_ws, size_t ws_size,
                              hipStream_t stream) {
  const float* x    = (const float*)d_in[0];
  const float* y    = (const float*)d_in[1];
  const float* Wimg = (const float*)d_in[2];
  const float* bimg = (const float*)d_in[3];
  const float* Wfea = (const float*)d_in[4];
  const float* bfea = (const float*)d_in[5];
  const float* W1   = (const float*)d_in[6];
  const float* W2   = (const float*)d_in[7];
  float* out = (float*)d_out;

  char* ws = (char*)d_ws;
  u16* wepad = (u16*)ws;                       //     19,968 B (96*104 bf16)
  u16* V     = (u16*)(ws + 32768);             // 12,582,912 B (65536 rows * 96 bf16)

  // zero V so pad cols 81..95 of every row are 0 (staging vector-loads them)
  hipMemsetAsync(V, 0, 65536 * (size_t)VSTR * 2, stream);
  k_conv<<<dim3(162, 3), 256, 0, stream>>>(x, y, Wimg, bimg, Wfea, bfea, W1, W2, V, wepad);
  k_att<<<dim3(8, 8, 32), 256, 0, stream>>>(V, wepad, out);
}